// Round 11
// baseline (143.473 us; speedup 1.0000x reference)
//
#include <hip/hip_runtime.h>
#include <hip/hip_cooperative_groups.h>
#include <stdint.h>

namespace cg = cooperative_groups;

using bf16x8_t = __attribute__((ext_vector_type(8))) __bf16;
using f32x4_t  = __attribute__((ext_vector_type(4))) float;
using u16x8_t  = __attribute__((ext_vector_type(8))) unsigned short;

#define KD 2048

static __device__ __forceinline__ unsigned short f2bf(float f) {
  union { float f; unsigned u; } v; v.f = f;
  unsigned r = v.u + 0x7fffu + ((v.u >> 16) & 1u);   // RNE
  return (unsigned short)(r >> 16);
}

// ---- single cooperative kernel: phase 1 = prep (roles by gid), grid-sync,
//      phase 2 = R10 main loop (BM=128, 8 waves, BK=64, counted-vmcnt). ----
// wbf3 layout (as R8-R10): elem ((s*9+nf)*64+l)*8+j <-> B[col=nf*16+(l&15)]
// [k=s*32+(l>>4)*8+j]; cols 0..63=w_a, 64..127=w_b, col 128=wsum, 129..143=0.
__global__ __launch_bounds__(512, 1) void k_fused(
    const float* __restrict__ x, const float* __restrict__ wqkv,
    const float* __restrict__ wz, const float* __restrict__ wb,
    const float* __restrict__ wa, unsigned short* __restrict__ wbf3,
    float* __restrict__ out)
{
  __shared__ __align__(16) unsigned char lds[135168];  // phase2: 98304 X | 36864 W
  const int t = threadIdx.x;
  const int lane = t & 63;

  // ================= phase 1: prep =================
  // blocks 0..63 (gid<32768):        W-pack (8 frags)
  // blocks 64..191 (gid<98304):      wsum column reduction -> frag 8 (col 128)
  // blocks 192..199 (gid<102400):    zero frag-8 cols 129..143
  {
    const int gid = blockIdx.x * 512 + t;
    const bool ws_role = (gid >= 32768) && (gid < 98304);
    float sv = 0.f;
    if (gid < 32768) {
      const int u = gid;
      const int l = u & 63;
      const int vv = u >> 6;
      const int nf = vv & 7;
      const int s  = vv >> 3;
      const int k  = s * 32 + ((l >> 4) << 3);
      const int c  = nf * 16 + (l & 15);
      const float* src = (c < 64) ? (wa + (size_t)c * KD + k)
                                  : (wb + (size_t)(c - 64) * KD + k);
      f32x4_t v0 = *(const f32x4_t*)(src);
      f32x4_t v1 = *(const f32x4_t*)(src + 4);
      u16x8_t o;
      o[0]=f2bf(v0[0]); o[1]=f2bf(v0[1]); o[2]=f2bf(v0[2]); o[3]=f2bf(v0[3]);
      o[4]=f2bf(v1[0]); o[5]=f2bf(v1[1]); o[6]=f2bf(v1[2]); o[7]=f2bf(v1[3]);
      *(u16x8_t*)(wbf3 + (size_t)((s * 9 + nf) * 64 + l) * 8) = o;
    } else if (ws_role) {
      const int u2 = gid - 32768;                  // 0..65535
      const int tt = u2 & 255;
      const int c8 = tt & 7;
      const int rg = tt >> 3;                      // 0..31
      const int h  = ((u2 >> 8) << 3) + c8;        // column 0..2047
      #pragma unroll 8
      for (int i = 0; i < 40; ++i) {
        const int r = rg + 32 * i;                 // 0..1279
        const float* p = (r < 768) ? (wqkv + (size_t)r * KD)
                                   : (wz + (size_t)(r - 768) * KD);
        sv += p[h];
      }
      sv += __shfl_xor(sv, 8, 64);
      sv += __shfl_xor(sv, 16, 64);
      sv += __shfl_xor(sv, 32, 64);
      if (lane < 8)
        ((float*)lds)[(t >> 8) * 32 + ((t >> 6) & 3) * 8 + lane] = sv;
    } else if (gid < 102400) {
      const int u3 = gid - 98304;                  // 0..4095
      const int s = u3 >> 6, l = u3 & 63;
      if (l & 15) {
        u16x8_t z; z[0]=0;z[1]=0;z[2]=0;z[3]=0;z[4]=0;z[5]=0;z[6]=0;z[7]=0;
        *(u16x8_t*)(wbf3 + (size_t)((s * 9 + 8) * 64 + l) * 8) = z;
      }
    }
    __syncthreads();
    if (ws_role && (t & 255) < 8) {
      const float* red = (float*)lds + (t >> 8) * 32;
      const float val = red[t & 7] + red[8 + (t & 7)] +
                        red[16 + (t & 7)] + red[24 + (t & 7)];
      const int hh = (((gid - 32768) >> 8) << 3) + (t & 7);   // k index 0..2047
      const int s9 = hh >> 5;
      const int g  = (hh & 31) >> 3;
      const int j  = hh & 7;
      wbf3[(size_t)((s9 * 9 + 8) * 64 + (g << 4)) * 8 + j] = f2bf(val);
    }
  }
  __threadfence();          // agent-scope release: wbf3 visible device-wide
  cg::this_grid().sync();

  // ================= phase 2: main (R10 verbatim) =================
  const int wv = t >> 6;          // 0..7
  const int g = lane >> 4;        // k-group 0..3
  const int r15 = lane & 15;
  const size_t tile = (size_t)blockIdx.x * 128;

  f32x4_t acc[9];
  #pragma unroll
  for (int i = 0; i < 9; ++i) acc[i] = f32x4_t{0.f, 0.f, 0.f, 0.f};

  // W stage: 18 chunks of 1KB (2 k-half steps x 9 frags, linear in wbf3);
  // wave wv takes {wv, wv+8}; waves 0,1 also take {16,17}.
  auto STAGE_W = [&](int it) {
    unsigned char* wbp = lds + 98304 + (it & 1) * 18432;
    const unsigned short* gw = wbf3 + (size_t)it * 9216 + lane * 8;
    __builtin_amdgcn_global_load_lds(
        (const __attribute__((address_space(1))) void*)(gw + wv * 512),
        (__attribute__((address_space(3))) void*)(wbp + wv * 1024), 16, 0, 0);
    __builtin_amdgcn_global_load_lds(
        (const __attribute__((address_space(1))) void*)(gw + (wv + 8) * 512),
        (__attribute__((address_space(3))) void*)(wbp + (wv + 8) * 1024), 16, 0, 0);
    if (wv < 2)
      __builtin_amdgcn_global_load_lds(
          (const __attribute__((address_space(1))) void*)(gw + (16 + wv) * 512),
          (__attribute__((address_space(3))) void*)(wbp + (16 + wv) * 1024), 16, 0, 0);
  };
  // X stage: 32 chunks of 1KB; chunk ch = rows ch*4..ch*4+3 (256 B/row).
  // Wave wv takes chunks wv*4..wv*4+3. lane l -> row ch*4+(l>>4), LDS slot
  // l&15 holds global 16B-slot (l&15)^(row&15) (XOR swizzle, involution).
  auto STAGE_X = [&](int it, int bsel) {
    unsigned char* xbp = lds + bsel * 32768;
    #pragma unroll
    for (int i = 0; i < 4; ++i) {
      const int ch = wv * 4 + i;                   // 0..31
      const int r = ch * 4 + (lane >> 4);          // row within tile 0..127
      const int c = (lane & 15) ^ (r & 15);        // source 16B slot
      const float* src = x + (tile + r) * KD + it * 64 + c * 4;
      __builtin_amdgcn_global_load_lds(
          (const __attribute__((address_space(1))) void*)src,
          (__attribute__((address_space(3))) void*)(xbp + ch * 1024), 16, 0, 0);
    }
  };
  auto COMPUTE = [&](int it, int xbsel) {
    const unsigned char* xbp = lds + xbsel * 32768;
    const unsigned char* wbp = lds + 98304 + (it & 1) * 18432;
    const int r = wv * 16 + r15;                   // 0..127 ; r&15 == r15
    const unsigned char* xr = xbp + r * 256;
    #pragma unroll
    for (int kh = 0; kh < 2; ++kh) {
      const int c0 = kh * 8 + g * 2;
      f32x4_t lo = *(const f32x4_t*)(xr + ((c0       ^ r15) * 16));
      f32x4_t hi = *(const f32x4_t*)(xr + (((c0 + 1) ^ r15) * 16));
      bf16x8_t af;
      af[0] = (__bf16)lo[0]; af[1] = (__bf16)lo[1];
      af[2] = (__bf16)lo[2]; af[3] = (__bf16)lo[3];
      af[4] = (__bf16)hi[0]; af[5] = (__bf16)hi[1];
      af[6] = (__bf16)hi[2]; af[7] = (__bf16)hi[3];
      #pragma unroll
      for (int nf = 0; nf < 9; ++nf) {
        bf16x8_t bfr = *(const bf16x8_t*)(wbp + ((kh * 9 + nf) * 64 + lane) * 16);
        acc[nf] = __builtin_amdgcn_mfma_f32_16x16x32_bf16(af, bfr, acc[nf], 0, 0, 0);
      }
    }
  };

  // prologue: per-wave queue [W(0):2-3, X(0):4, X(1):4]
  STAGE_W(0);
  STAGE_X(0, 0);
  STAGE_X(1, 1);

  int xb = 0;                                      // buffer of tile `it` (it % 3)
  for (int it = 0; it < 31; ++it) {
    // drains W(it), X(it); leaves X(it+1) (4 loads/wave = 32 KB/CU) in flight
    asm volatile("s_waitcnt vmcnt(4)" ::: "memory");
    __builtin_amdgcn_s_barrier();
    __builtin_amdgcn_sched_barrier(0);
    STAGE_W(it + 1);                               // buf (it+1)&1, freed by barrier
    if (it < 30) {
      int b2 = xb + 2; if (b2 >= 3) b2 -= 3;
      STAGE_X(it + 2, b2);                         // buf (it+2)%3, freed by barrier
    }
    COMPUTE(it, xb);
    ++xb; if (xb == 3) xb = 0;
  }
  // peeled last step: full drain
  asm volatile("s_waitcnt vmcnt(0)" ::: "memory");
  __builtin_amdgcn_s_barrier();
  __builtin_amdgcn_sched_barrier(0);
  COMPUTE(31, xb);

  // epilogue: C col=lane&15, row=g*4+reg; a-frag nf pairs with b-frag nf+4.
  // acc[8][r] (col 128) = qkv+z fold, already at the writer lane (r15==0).
  #pragma unroll
  for (int r = 0; r < 4; ++r) {
    float v = 0.f;
    #pragma unroll
    for (int nf = 0; nf < 4; ++nf) {
      float av = acc[nf][r];
      float bv = acc[nf + 4][r];
      v += av / (1.f + __expf(-bv));          // a * sigmoid(b)
    }
    v += __shfl_xor(v, 1, 64);
    v += __shfl_xor(v, 2, 64);
    v += __shfl_xor(v, 4, 64);
    v += __shfl_xor(v, 8, 64);
    if (r15 == 0) out[tile + wv * 16 + g * 4 + r] = v + acc[8][r];
  }
}

extern "C" void kernel_launch(void* const* d_in, const int* in_sizes, int n_in,
                              void* d_out, int out_size, void* d_ws, size_t ws_size,
                              hipStream_t stream) {
  const float* x    = (const float*)d_in[0];
  const float* wqkv = (const float*)d_in[1];
  const float* wz   = (const float*)d_in[2];
  const float* wb   = (const float*)d_in[3];   // dict order: w_b before w_a
  const float* wa   = (const float*)d_in[4];
  float* out = (float*)d_out;

  unsigned short* wbf3 = (unsigned short*)d_ws;  // 64*9*64*8 shorts = 576 KB

  void* args[7];
  args[0] = (void*)&x;
  args[1] = (void*)&wqkv;
  args[2] = (void*)&wz;
  args[3] = (void*)&wb;
  args[4] = (void*)&wa;
  args[5] = (void*)&wbf3;
  args[6] = (void*)&out;
  hipLaunchCooperativeKernel((const void*)k_fused,
                             dim3(out_size / 128), dim3(512),
                             args, 0, stream);
}

// Round 12
// 113.494 us; speedup vs baseline: 1.2641x; 1.2641x over previous
//
#include <hip/hip_runtime.h>
#include <stdint.h>

using bf16x8_t = __attribute__((ext_vector_type(8))) __bf16;
using f32x4_t  = __attribute__((ext_vector_type(4))) float;
using u16x8_t  = __attribute__((ext_vector_type(8))) unsigned short;

#define KD 2048

static __device__ __forceinline__ unsigned short f2bf(float f) {
  union { float f; unsigned u; } v; v.f = f;
  unsigned r = v.u + 0x7fffu + ((v.u >> 16) & 1u);   // RNE
  return (unsigned short)(r >> 16);
}

// ---- single fused kernel, manual device-scope barrier between phases ----
// phase 1 roles by gid (131072 threads): gid<32768 W-pack; 32768..98303 wsum
// tree-reduce -> frag-8 col 128; 98304..102399 zero frag-8 cols 129..143.
// phase 2 = R10 main loop (BM=128, 8 waves, BK=64, counted-vmcnt pipeline).
// wbf3 layout: elem ((s*9+nf)*64+l)*8+j <-> B[col=nf*16+(l&15)]
// [k=s*32+(l>>4)*8+j]; cols 0..63=w_a, 64..127=w_b, col 128=wsum, 129..143=0.
__global__ __launch_bounds__(512, 1) void k_fused(
    const float* __restrict__ x, const float* __restrict__ wqkv,
    const float* __restrict__ wz, const float* __restrict__ wb,
    const float* __restrict__ wa, unsigned short* __restrict__ wbf3,
    unsigned int* __restrict__ cnt, float* __restrict__ out)
{
  __shared__ __align__(16) unsigned char lds[135168];  // phase2: 98304 X | 36864 W
  const int t = threadIdx.x;
  const int lane = t & 63;

  // ================= phase 1: prep =================
  {
    const int gid = blockIdx.x * 512 + t;
    const bool ws_role = (gid >= 32768) && (gid < 98304);
    float sv = 0.f;
    if (gid < 32768) {
      const int u = gid;
      const int l = u & 63;
      const int vv = u >> 6;
      const int nf = vv & 7;
      const int s  = vv >> 3;
      const int k  = s * 32 + ((l >> 4) << 3);
      const int c  = nf * 16 + (l & 15);
      const float* src = (c < 64) ? (wa + (size_t)c * KD + k)
                                  : (wb + (size_t)(c - 64) * KD + k);
      f32x4_t v0 = *(const f32x4_t*)(src);
      f32x4_t v1 = *(const f32x4_t*)(src + 4);
      u16x8_t o;
      o[0]=f2bf(v0[0]); o[1]=f2bf(v0[1]); o[2]=f2bf(v0[2]); o[3]=f2bf(v0[3]);
      o[4]=f2bf(v1[0]); o[5]=f2bf(v1[1]); o[6]=f2bf(v1[2]); o[7]=f2bf(v1[3]);
      *(u16x8_t*)(wbf3 + (size_t)((s * 9 + nf) * 64 + l) * 8) = o;
    } else if (ws_role) {
      const int u2 = gid - 32768;                  // 0..65535
      const int tt = u2 & 255;
      const int c8 = tt & 7;
      const int rg = tt >> 3;                      // 0..31
      const int h  = ((u2 >> 8) << 3) + c8;        // column 0..2047
      #pragma unroll 8
      for (int i = 0; i < 40; ++i) {
        const int r = rg + 32 * i;                 // 0..1279
        const float* p = (r < 768) ? (wqkv + (size_t)r * KD)
                                   : (wz + (size_t)(r - 768) * KD);
        sv += p[h];
      }
      sv += __shfl_xor(sv, 8, 64);
      sv += __shfl_xor(sv, 16, 64);
      sv += __shfl_xor(sv, 32, 64);
      if (lane < 8)
        ((float*)lds)[(t >> 8) * 32 + ((t >> 6) & 3) * 8 + lane] = sv;
    } else if (gid < 102400) {
      const int u3 = gid - 98304;                  // 0..4095
      const int s = u3 >> 6, l = u3 & 63;
      if (l & 15) {
        u16x8_t z; z[0]=0;z[1]=0;z[2]=0;z[3]=0;z[4]=0;z[5]=0;z[6]=0;z[7]=0;
        *(u16x8_t*)(wbf3 + (size_t)((s * 9 + 8) * 64 + l) * 8) = z;
      }
    }
    __syncthreads();
    if (ws_role && (t & 255) < 8) {
      const float* red = (float*)lds + (t >> 8) * 32;
      const float val = red[t & 7] + red[8 + (t & 7)] +
                        red[16 + (t & 7)] + red[24 + (t & 7)];
      const int hh = (((gid - 32768) >> 8) << 3) + (t & 7);   // k index 0..2047
      const int s9 = hh >> 5;
      const int g  = (hh & 31) >> 3;
      const int j  = hh & 7;
      wbf3[(size_t)((s9 * 9 + 8) * 64 + (g << 4)) * 8 + j] = f2bf(val);
    }
  }

  // ================= manual grid barrier (device-memory, device-scope) ====
  __syncthreads();                      // all waves' stores drained to L2
  if (t == 0) {
    __threadfence();                    // release: write back this XCD's L2
    atomicAdd(cnt, 1u);
    while (__hip_atomic_load(cnt, __ATOMIC_ACQUIRE, __HIP_MEMORY_SCOPE_AGENT)
           < 256u)
      __builtin_amdgcn_s_sleep(2);
  }
  __syncthreads();
  __threadfence();                      // acquire per wave: invalidate stale L1/L2

  // ================= phase 2: main (R10 verbatim) =================
  const int wv = t >> 6;          // 0..7
  const int g = lane >> 4;        // k-group 0..3
  const int r15 = lane & 15;
  const size_t tile = (size_t)blockIdx.x * 128;

  f32x4_t acc[9];
  #pragma unroll
  for (int i = 0; i < 9; ++i) acc[i] = f32x4_t{0.f, 0.f, 0.f, 0.f};

  // W stage: 18 chunks of 1KB (2 k-half steps x 9 frags, linear in wbf3);
  // wave wv takes {wv, wv+8}; waves 0,1 also take {16,17}.
  auto STAGE_W = [&](int it) {
    unsigned char* wbp = lds + 98304 + (it & 1) * 18432;
    const unsigned short* gw = wbf3 + (size_t)it * 9216 + lane * 8;
    __builtin_amdgcn_global_load_lds(
        (const __attribute__((address_space(1))) void*)(gw + wv * 512),
        (__attribute__((address_space(3))) void*)(wbp + wv * 1024), 16, 0, 0);
    __builtin_amdgcn_global_load_lds(
        (const __attribute__((address_space(1))) void*)(gw + (wv + 8) * 512),
        (__attribute__((address_space(3))) void*)(wbp + (wv + 8) * 1024), 16, 0, 0);
    if (wv < 2)
      __builtin_amdgcn_global_load_lds(
          (const __attribute__((address_space(1))) void*)(gw + (16 + wv) * 512),
          (__attribute__((address_space(3))) void*)(wbp + (16 + wv) * 1024), 16, 0, 0);
  };
  // X stage: 32 chunks of 1KB; chunk ch = rows ch*4..ch*4+3 (256 B/row).
  // Wave wv takes chunks wv*4..wv*4+3. lane l -> row ch*4+(l>>4), LDS slot
  // l&15 holds global 16B-slot (l&15)^(row&15) (XOR swizzle, involution).
  auto STAGE_X = [&](int it, int bsel) {
    unsigned char* xbp = lds + bsel * 32768;
    #pragma unroll
    for (int i = 0; i < 4; ++i) {
      const int ch = wv * 4 + i;                   // 0..31
      const int r = ch * 4 + (lane >> 4);          // row within tile 0..127
      const int c = (lane & 15) ^ (r & 15);        // source 16B slot
      const float* src = x + (tile + r) * KD + it * 64 + c * 4;
      __builtin_amdgcn_global_load_lds(
          (const __attribute__((address_space(1))) void*)src,
          (__attribute__((address_space(3))) void*)(xbp + ch * 1024), 16, 0, 0);
    }
  };
  auto COMPUTE = [&](int it, int xbsel) {
    const unsigned char* xbp = lds + xbsel * 32768;
    const unsigned char* wbp = lds + 98304 + (it & 1) * 18432;
    const int r = wv * 16 + r15;                   // 0..127 ; r&15 == r15
    const unsigned char* xr = xbp + r * 256;
    #pragma unroll
    for (int kh = 0; kh < 2; ++kh) {
      const int c0 = kh * 8 + g * 2;
      f32x4_t lo = *(const f32x4_t*)(xr + ((c0       ^ r15) * 16));
      f32x4_t hi = *(const f32x4_t*)(xr + (((c0 + 1) ^ r15) * 16));
      bf16x8_t af;
      af[0] = (__bf16)lo[0]; af[1] = (__bf16)lo[1];
      af[2] = (__bf16)lo[2]; af[3] = (__bf16)lo[3];
      af[4] = (__bf16)hi[0]; af[5] = (__bf16)hi[1];
      af[6] = (__bf16)hi[2]; af[7] = (__bf16)hi[3];
      #pragma unroll
      for (int nf = 0; nf < 9; ++nf) {
        bf16x8_t bfr = *(const bf16x8_t*)(wbp + ((kh * 9 + nf) * 64 + lane) * 16);
        acc[nf] = __builtin_amdgcn_mfma_f32_16x16x32_bf16(af, bfr, acc[nf], 0, 0, 0);
      }
    }
  };

  // prologue: per-wave queue [W(0):2-3, X(0):4, X(1):4]
  STAGE_W(0);
  STAGE_X(0, 0);
  STAGE_X(1, 1);

  int xb = 0;                                      // buffer of tile `it` (it % 3)
  for (int it = 0; it < 31; ++it) {
    // drains W(it), X(it); leaves X(it+1) (4 loads/wave = 32 KB/CU) in flight
    asm volatile("s_waitcnt vmcnt(4)" ::: "memory");
    __builtin_amdgcn_s_barrier();
    __builtin_amdgcn_sched_barrier(0);
    STAGE_W(it + 1);                               // buf (it+1)&1, freed by barrier
    if (it < 30) {
      int b2 = xb + 2; if (b2 >= 3) b2 -= 3;
      STAGE_X(it + 2, b2);                         // buf (it+2)%3, freed by barrier
    }
    COMPUTE(it, xb);
    ++xb; if (xb == 3) xb = 0;
  }
  // peeled last step: full drain
  asm volatile("s_waitcnt vmcnt(0)" ::: "memory");
  __builtin_amdgcn_s_barrier();
  __builtin_amdgcn_sched_barrier(0);
  COMPUTE(31, xb);

  // epilogue: C col=lane&15, row=g*4+reg; a-frag nf pairs with b-frag nf+4.
  // acc[8][r] (col 128) = qkv+z fold, already at the writer lane (r15==0).
  #pragma unroll
  for (int r = 0; r < 4; ++r) {
    float v = 0.f;
    #pragma unroll
    for (int nf = 0; nf < 4; ++nf) {
      float av = acc[nf][r];
      float bv = acc[nf + 4][r];
      v += av / (1.f + __expf(-bv));          // a * sigmoid(b)
    }
    v += __shfl_xor(v, 1, 64);
    v += __shfl_xor(v, 2, 64);
    v += __shfl_xor(v, 4, 64);
    v += __shfl_xor(v, 8, 64);
    if (r15 == 0) out[tile + wv * 16 + g * 4 + r] = v + acc[8][r];
  }
}

extern "C" void kernel_launch(void* const* d_in, const int* in_sizes, int n_in,
                              void* d_out, int out_size, void* d_ws, size_t ws_size,
                              hipStream_t stream) {
  const float* x    = (const float*)d_in[0];
  const float* wqkv = (const float*)d_in[1];
  const float* wz   = (const float*)d_in[2];
  const float* wb   = (const float*)d_in[3];   // dict order: w_b before w_a
  const float* wa   = (const float*)d_in[4];
  float* out = (float*)d_out;

  unsigned short* wbf3 = (unsigned short*)d_ws;            // 576 KB pre-frag W
  unsigned int* cnt = (unsigned int*)((char*)d_ws + (1 << 20));  // barrier counter

  hipMemsetAsync(cnt, 0, 4, stream);                       // graph-capturable
  k_fused<<<out_size / 128, 512, 0, stream>>>(x, wqkv, wz, wb, wa, wbf3, cnt, out);
}

// Round 13
// 76.712 us; speedup vs baseline: 1.8703x; 1.4795x over previous
//
#include <hip/hip_runtime.h>
#include <stdint.h>

using bf16x8_t = __attribute__((ext_vector_type(8))) __bf16;
using f32x4_t  = __attribute__((ext_vector_type(4))) float;
using u16x8_t  = __attribute__((ext_vector_type(8))) unsigned short;

#define KD 2048

static __device__ __forceinline__ unsigned short f2bf(float f) {
  union { float f; unsigned u; } v; v.f = f;
  unsigned r = v.u + 0x7fffu + ((v.u >> 16) & 1u);   // RNE
  return (unsigned short)(r >> 16);
}

// ---- single fused kernel, manual device-scope barrier between phases ----
// phase 1 roles by gid (131072 threads): gid<32768 W-pack; 32768..98303 wsum
// tree-reduce -> frag-8 col 128; 98304..102399 zero frag-8 cols 129..143.
// phase 2 = R10 main loop (BM=128, 8 waves, BK=64, counted-vmcnt pipeline).
// Barrier: release = syncthreads + t0 threadfence + atomicAdd (R12-proven);
// poll = RELAXED loads (no per-poll cache invalidate!); acquire = ONE
// ACQUIRE load by t0 after loop, then syncthreads. This removes R12's two
// invalidate storms (acquire-per-poll, per-thread fence).
__global__ __launch_bounds__(512, 1) void k_fused(
    const float* __restrict__ x, const float* __restrict__ wqkv,
    const float* __restrict__ wz, const float* __restrict__ wb,
    const float* __restrict__ wa, unsigned short* __restrict__ wbf3,
    unsigned int* __restrict__ cnt, float* __restrict__ out)
{
  __shared__ __align__(16) unsigned char lds[135168];  // phase2: 98304 X | 36864 W
  const int t = threadIdx.x;
  const int lane = t & 63;

  // ================= phase 1: prep =================
  {
    const int gid = blockIdx.x * 512 + t;
    const bool ws_role = (gid >= 32768) && (gid < 98304);
    float sv = 0.f;
    if (gid < 32768) {
      const int u = gid;
      const int l = u & 63;
      const int vv = u >> 6;
      const int nf = vv & 7;
      const int s  = vv >> 3;
      const int k  = s * 32 + ((l >> 4) << 3);
      const int c  = nf * 16 + (l & 15);
      const float* src = (c < 64) ? (wa + (size_t)c * KD + k)
                                  : (wb + (size_t)(c - 64) * KD + k);
      f32x4_t v0 = *(const f32x4_t*)(src);
      f32x4_t v1 = *(const f32x4_t*)(src + 4);
      u16x8_t o;
      o[0]=f2bf(v0[0]); o[1]=f2bf(v0[1]); o[2]=f2bf(v0[2]); o[3]=f2bf(v0[3]);
      o[4]=f2bf(v1[0]); o[5]=f2bf(v1[1]); o[6]=f2bf(v1[2]); o[7]=f2bf(v1[3]);
      *(u16x8_t*)(wbf3 + (size_t)((s * 9 + nf) * 64 + l) * 8) = o;
    } else if (ws_role) {
      const int u2 = gid - 32768;                  // 0..65535
      const int tt = u2 & 255;
      const int c8 = tt & 7;
      const int rg = tt >> 3;                      // 0..31
      const int h  = ((u2 >> 8) << 3) + c8;        // column 0..2047
      #pragma unroll 8
      for (int i = 0; i < 40; ++i) {
        const int r = rg + 32 * i;                 // 0..1279
        const float* p = (r < 768) ? (wqkv + (size_t)r * KD)
                                   : (wz + (size_t)(r - 768) * KD);
        sv += p[h];
      }
      sv += __shfl_xor(sv, 8, 64);
      sv += __shfl_xor(sv, 16, 64);
      sv += __shfl_xor(sv, 32, 64);
      if (lane < 8)
        ((float*)lds)[(t >> 8) * 32 + ((t >> 6) & 3) * 8 + lane] = sv;
    } else if (gid < 102400) {
      const int u3 = gid - 98304;                  // 0..4095
      const int s = u3 >> 6, l = u3 & 63;
      if (l & 15) {
        u16x8_t z; z[0]=0;z[1]=0;z[2]=0;z[3]=0;z[4]=0;z[5]=0;z[6]=0;z[7]=0;
        *(u16x8_t*)(wbf3 + (size_t)((s * 9 + 8) * 64 + l) * 8) = z;
      }
    }
    __syncthreads();
    if (ws_role && (t & 255) < 8) {
      const float* red = (float*)lds + (t >> 8) * 32;
      const float val = red[t & 7] + red[8 + (t & 7)] +
                        red[16 + (t & 7)] + red[24 + (t & 7)];
      const int hh = (((gid - 32768) >> 8) << 3) + (t & 7);   // k index 0..2047
      const int s9 = hh >> 5;
      const int g  = (hh & 31) >> 3;
      const int j  = hh & 7;
      wbf3[(size_t)((s9 * 9 + 8) * 64 + (g << 4)) * 8 + j] = f2bf(val);
    }
  }

  // ====== manual grid barrier: relaxed poll, single acquire per block ======
  __syncthreads();                      // block's stores drained to its L2
  if (t == 0) {
    __threadfence();                    // release: write back this XCD's L2
    atomicAdd(cnt, 1u);
    while (__hip_atomic_load(cnt, __ATOMIC_RELAXED, __HIP_MEMORY_SCOPE_AGENT)
           < 256u)
      __builtin_amdgcn_s_sleep(8);      // ~0.2 us between polls, no invalidates
    // one acquire: invalidate this CU's L1 + XCD L2 exactly once
    (void)__hip_atomic_load(cnt, __ATOMIC_ACQUIRE, __HIP_MEMORY_SCOPE_AGENT);
  }
  __syncthreads();                      // rest of block ordered behind t0

  // ================= phase 2: main (R10 verbatim) =================
  const int wv = t >> 6;          // 0..7
  const int g = lane >> 4;        // k-group 0..3
  const int r15 = lane & 15;
  const size_t tile = (size_t)blockIdx.x * 128;

  f32x4_t acc[9];
  #pragma unroll
  for (int i = 0; i < 9; ++i) acc[i] = f32x4_t{0.f, 0.f, 0.f, 0.f};

  // W stage: 18 chunks of 1KB (2 k-half steps x 9 frags, linear in wbf3);
  // wave wv takes {wv, wv+8}; waves 0,1 also take {16,17}.
  auto STAGE_W = [&](int it) {
    unsigned char* wbp = lds + 98304 + (it & 1) * 18432;
    const unsigned short* gw = wbf3 + (size_t)it * 9216 + lane * 8;
    __builtin_amdgcn_global_load_lds(
        (const __attribute__((address_space(1))) void*)(gw + wv * 512),
        (__attribute__((address_space(3))) void*)(wbp + wv * 1024), 16, 0, 0);
    __builtin_amdgcn_global_load_lds(
        (const __attribute__((address_space(1))) void*)(gw + (wv + 8) * 512),
        (__attribute__((address_space(3))) void*)(wbp + (wv + 8) * 1024), 16, 0, 0);
    if (wv < 2)
      __builtin_amdgcn_global_load_lds(
          (const __attribute__((address_space(1))) void*)(gw + (16 + wv) * 512),
          (__attribute__((address_space(3))) void*)(wbp + (16 + wv) * 1024), 16, 0, 0);
  };
  // X stage: 32 chunks of 1KB; chunk ch = rows ch*4..ch*4+3 (256 B/row).
  // Wave wv takes chunks wv*4..wv*4+3. lane l -> row ch*4+(l>>4), LDS slot
  // l&15 holds global 16B-slot (l&15)^(row&15) (XOR swizzle, involution).
  auto STAGE_X = [&](int it, int bsel) {
    unsigned char* xbp = lds + bsel * 32768;
    #pragma unroll
    for (int i = 0; i < 4; ++i) {
      const int ch = wv * 4 + i;                   // 0..31
      const int r = ch * 4 + (lane >> 4);          // row within tile 0..127
      const int c = (lane & 15) ^ (r & 15);        // source 16B slot
      const float* src = x + (tile + r) * KD + it * 64 + c * 4;
      __builtin_amdgcn_global_load_lds(
          (const __attribute__((address_space(1))) void*)src,
          (__attribute__((address_space(3))) void*)(xbp + ch * 1024), 16, 0, 0);
    }
  };
  auto COMPUTE = [&](int it, int xbsel) {
    const unsigned char* xbp = lds + xbsel * 32768;
    const unsigned char* wbp = lds + 98304 + (it & 1) * 18432;
    const int r = wv * 16 + r15;                   // 0..127 ; r&15 == r15
    const unsigned char* xr = xbp + r * 256;
    #pragma unroll
    for (int kh = 0; kh < 2; ++kh) {
      const int c0 = kh * 8 + g * 2;
      f32x4_t lo = *(const f32x4_t*)(xr + ((c0       ^ r15) * 16));
      f32x4_t hi = *(const f32x4_t*)(xr + (((c0 + 1) ^ r15) * 16));
      bf16x8_t af;
      af[0] = (__bf16)lo[0]; af[1] = (__bf16)lo[1];
      af[2] = (__bf16)lo[2]; af[3] = (__bf16)lo[3];
      af[4] = (__bf16)hi[0]; af[5] = (__bf16)hi[1];
      af[6] = (__bf16)hi[2]; af[7] = (__bf16)hi[3];
      #pragma unroll
      for (int nf = 0; nf < 9; ++nf) {
        bf16x8_t bfr = *(const bf16x8_t*)(wbp + ((kh * 9 + nf) * 64 + lane) * 16);
        acc[nf] = __builtin_amdgcn_mfma_f32_16x16x32_bf16(af, bfr, acc[nf], 0, 0, 0);
      }
    }
  };

  // prologue: per-wave queue [W(0):2-3, X(0):4, X(1):4]
  STAGE_W(0);
  STAGE_X(0, 0);
  STAGE_X(1, 1);

  int xb = 0;                                      // buffer of tile `it` (it % 3)
  for (int it = 0; it < 31; ++it) {
    // drains W(it), X(it); leaves X(it+1) (4 loads/wave = 32 KB/CU) in flight
    asm volatile("s_waitcnt vmcnt(4)" ::: "memory");
    __builtin_amdgcn_s_barrier();
    __builtin_amdgcn_sched_barrier(0);
    STAGE_W(it + 1);                               // buf (it+1)&1, freed by barrier
    if (it < 30) {
      int b2 = xb + 2; if (b2 >= 3) b2 -= 3;
      STAGE_X(it + 2, b2);                         // buf (it+2)%3, freed by barrier
    }
    COMPUTE(it, xb);
    ++xb; if (xb == 3) xb = 0;
  }
  // peeled last step: full drain
  asm volatile("s_waitcnt vmcnt(0)" ::: "memory");
  __builtin_amdgcn_s_barrier();
  __builtin_amdgcn_sched_barrier(0);
  COMPUTE(31, xb);

  // epilogue: C col=lane&15, row=g*4+reg; a-frag nf pairs with b-frag nf+4.
  // acc[8][r] (col 128) = qkv+z fold, already at the writer lane (r15==0).
  #pragma unroll
  for (int r = 0; r < 4; ++r) {
    float v = 0.f;
    #pragma unroll
    for (int nf = 0; nf < 4; ++nf) {
      float av = acc[nf][r];
      float bv = acc[nf + 4][r];
      v += av / (1.f + __expf(-bv));          // a * sigmoid(b)
    }
    v += __shfl_xor(v, 1, 64);
    v += __shfl_xor(v, 2, 64);
    v += __shfl_xor(v, 4, 64);
    v += __shfl_xor(v, 8, 64);
    if (r15 == 0) out[tile + wv * 16 + g * 4 + r] = v + acc[8][r];
  }
}

extern "C" void kernel_launch(void* const* d_in, const int* in_sizes, int n_in,
                              void* d_out, int out_size, void* d_ws, size_t ws_size,
                              hipStream_t stream) {
  const float* x    = (const float*)d_in[0];
  const float* wqkv = (const float*)d_in[1];
  const float* wz   = (const float*)d_in[2];
  const float* wb   = (const float*)d_in[3];   // dict order: w_b before w_a
  const float* wa   = (const float*)d_in[4];
  float* out = (float*)d_out;

  unsigned short* wbf3 = (unsigned short*)d_ws;            // 576 KB pre-frag W
  unsigned int* cnt = (unsigned int*)((char*)d_ws + (1 << 20));  // barrier counter

  hipMemsetAsync(cnt, 0, 4, stream);                       // graph-capturable
  k_fused<<<out_size / 128, 512, 0, stream>>>(x, wqkv, wz, wb, wa, wbf3, cnt, out);
}

// Round 14
// 56.153 us; speedup vs baseline: 2.5550x; 1.3661x over previous
//
#include <hip/hip_runtime.h>
#include <stdint.h>

using bf16x8_t = __attribute__((ext_vector_type(8))) __bf16;
using f32x4_t  = __attribute__((ext_vector_type(4))) float;
using u16x8_t  = __attribute__((ext_vector_type(8))) unsigned short;

#define KD 2048

static __device__ __forceinline__ unsigned short f2bf(float f) {
  union { float f; unsigned u; } v; v.f = f;
  unsigned r = v.u + 0x7fffu + ((v.u >> 16) & 1u);   // RNE
  return (unsigned short)(r >> 16);
}

// ---- fused prep (R7 verbatim, proven): grid 384 ----
// blocks 0..127: pack 8-frag bf16 W: elem ((s*8+nf)*64+l)*8+j <->
//   B[col=nf*16+(l&15)][k=s*32+(l>>4)*8+j]; cols 0..63=w_a, 64..127=w_b.
// blocks 128..383: wsum[h]=sum_d wqkv[d][h]+wz[d][h] (fp32, fixed tree).
__global__ void k_prep(const float* __restrict__ wqkv, const float* __restrict__ wz,
                       const float* __restrict__ wb, const float* __restrict__ wa,
                       float* __restrict__ wsum, unsigned short* __restrict__ wbf3) {
  __shared__ float red[4][8];
  const int b = blockIdx.x, t = threadIdx.x;
  if (b < 128) {
    const int u = b * 256 + t;
    const int l = u & 63;
    const int vv = u >> 6;
    const int nf = vv & 7;
    const int s  = vv >> 3;
    const int k  = s * 32 + ((l >> 4) << 3);
    const int c  = nf * 16 + (l & 15);
    const float* src = (c < 64) ? (wa + (size_t)c * KD + k)
                                : (wb + (size_t)(c - 64) * KD + k);
    f32x4_t v0 = *(const f32x4_t*)(src);
    f32x4_t v1 = *(const f32x4_t*)(src + 4);
    u16x8_t o;
    o[0]=f2bf(v0[0]); o[1]=f2bf(v0[1]); o[2]=f2bf(v0[2]); o[3]=f2bf(v0[3]);
    o[4]=f2bf(v1[0]); o[5]=f2bf(v1[1]); o[6]=f2bf(v1[2]); o[7]=f2bf(v1[3]);
    *(u16x8_t*)(wbf3 + (size_t)u * 8) = o;
  } else {
    const int bw = b - 128;                      // cols h = bw*8 .. bw*8+7
    const int c = t & 7;
    const int rg = t >> 3;                       // 0..31
    const int h = bw * 8 + c;
    float s = 0.f;
    #pragma unroll 8
    for (int i = 0; i < 40; ++i) {
      const int r = rg + 32 * i;                 // 0..1279
      const float* p = (r < 768) ? (wqkv + (size_t)r * KD)
                                 : (wz + (size_t)(r - 768) * KD);
      s += p[h];
    }
    s += __shfl_xor(s, 8, 64);
    s += __shfl_xor(s, 16, 64);
    s += __shfl_xor(s, 32, 64);
    const int lane = t & 63, wv = t >> 6;
    if (lane < 8) red[wv][lane] = s;
    __syncthreads();
    if (t < 8) wsum[bw * 8 + t] = red[0][t] + red[1][t] + red[2][t] + red[3][t];
  }
}

// ---- main: BM=128 (8 waves x 16 rows), BK=64, 32 K-steps, 8 W-frags.
// W: staged in PAIRS (2 K-steps = 32KB + 512B wsum appendix) 2 iters ahead,
//    validated by a barrier every SECOND iteration (16 barriers total).
// X: 2 bufs, LATE-staged (X(it+2) issued after compute(it) frees its buf) —
//    wave-private rows, no barrier needed; same 32KB/CU in-flight nadir.
// Per-wave uniform counts: W-pair stage = 6 instrs, X stage = 4. Waits:
// even it -> vmcnt(4) [drains Wpair(it)+X(it), leaves X(it+1)];
// odd it  -> vmcnt(10) [drains X(it), leaves Wpair(next)+X(it+1)]; last -> 0.
// s0 = fp32 VALU dot vs wsum slice read from the W-pair LDS appendix.
// LDS: 2x32K X | 2x33280 W-pair = 129 KB -> 1 block/CU, grid 256.
__global__ __launch_bounds__(512, 1) void k_main(
    const float* __restrict__ x, const unsigned short* __restrict__ wbf3,
    const float* __restrict__ wsum, float* __restrict__ out)
{
  __shared__ __align__(16) unsigned char lds[132096];  // 65536 X | 66560 W
  const int t = threadIdx.x;
  const int lane = t & 63;
  const int wv = t >> 6;          // 0..7
  const int g = lane >> 4;        // k-group 0..3
  const int r15 = lane & 15;
  const size_t tile = (size_t)blockIdx.x * 128;

  f32x4_t acc[8];
  #pragma unroll
  for (int i = 0; i < 8; ++i) acc[i] = f32x4_t{0.f, 0.f, 0.f, 0.f};
  float s0 = 0.f;

  // W pair j covers K-steps {2j, 2j+1}: 32 chunks of 1KB + 512B wsum appendix.
  // Wave wv stages chunks wv*4..wv*4+3; ALL waves duplicate the 2 appendix
  // loads (width=4, identical data -> benign WAW) so counts stay uniform (6).
  auto STAGE_WP = [&](int j) {
    unsigned char* wbp = lds + 65536 + (j & 1) * 33280;
    const unsigned short* gw = wbf3 + (size_t)j * 16384 + lane * 8;
    #pragma unroll
    for (int i = 0; i < 4; ++i) {
      const int ch = wv * 4 + i;
      __builtin_amdgcn_global_load_lds(
          (const __attribute__((address_space(1))) void*)(gw + ch * 512),
          (__attribute__((address_space(3))) void*)(wbp + ch * 1024), 16, 0, 0);
    }
    const float* gws = wsum + j * 128 + lane;
    __builtin_amdgcn_global_load_lds(
        (const __attribute__((address_space(1))) void*)gws,
        (__attribute__((address_space(3))) void*)(wbp + 32768), 4, 0, 0);
    __builtin_amdgcn_global_load_lds(
        (const __attribute__((address_space(1))) void*)(gws + 64),
        (__attribute__((address_space(3))) void*)(wbp + 32768 + 256), 4, 0, 0);
  };
  // X: 32 chunks of 1KB; chunk ch = rows ch*4..ch*4+3 (256B/row). Wave wv
  // stages chunks wv*4..wv*4+3 (its own 16 rows). lane l -> row ch*4+(l>>4),
  // LDS slot l&15 holds global 16B-slot (l&15)^(row&15) (XOR involution).
  auto STAGE_X = [&](int it) {
    unsigned char* xbp = lds + (it & 1) * 32768;
    #pragma unroll
    for (int i = 0; i < 4; ++i) {
      const int ch = wv * 4 + i;                   // 0..31
      const int r = ch * 4 + (lane >> 4);          // row within tile 0..127
      const int c = (lane & 15) ^ (r & 15);        // source 16B slot
      const float* src = x + (tile + r) * KD + it * 64 + c * 4;
      __builtin_amdgcn_global_load_lds(
          (const __attribute__((address_space(1))) void*)src,
          (__attribute__((address_space(3))) void*)(xbp + ch * 1024), 16, 0, 0);
    }
  };
  auto COMPUTE = [&](int it) {
    const unsigned char* xbp = lds + (it & 1) * 32768;
    const unsigned char* wpb = lds + 65536 + ((it >> 1) & 1) * 33280;
    const unsigned char* wbp = wpb + (it & 1) * 16384;
    const float* wsp = (const float*)(wpb + 32768 + (it & 1) * 256);
    const int r = wv * 16 + r15;                   // 0..127 ; r&15 == r15
    const unsigned char* xr = xbp + r * 256;
    #pragma unroll
    for (int kh = 0; kh < 2; ++kh) {
      const int c0 = kh * 8 + g * 2;
      f32x4_t lo = *(const f32x4_t*)(xr + ((c0       ^ r15) * 16));
      f32x4_t hi = *(const f32x4_t*)(xr + (((c0 + 1) ^ r15) * 16));
      f32x4_t w0 = *(const f32x4_t*)(wsp + kh * 32 + g * 8);
      f32x4_t w1 = *(const f32x4_t*)(wsp + kh * 32 + g * 8 + 4);
      bf16x8_t af;
      af[0] = (__bf16)lo[0]; af[1] = (__bf16)lo[1];
      af[2] = (__bf16)lo[2]; af[3] = (__bf16)lo[3];
      af[4] = (__bf16)hi[0]; af[5] = (__bf16)hi[1];
      af[6] = (__bf16)hi[2]; af[7] = (__bf16)hi[3];
      s0 += lo[0]*w0[0] + lo[1]*w0[1] + lo[2]*w0[2] + lo[3]*w0[3]
          + hi[0]*w1[0] + hi[1]*w1[1] + hi[2]*w1[2] + hi[3]*w1[3];
      #pragma unroll
      for (int nf = 0; nf < 8; ++nf) {
        bf16x8_t bfr = *(const bf16x8_t*)(wbp + ((kh * 8 + nf) * 64 + lane) * 16);
        acc[nf] = __builtin_amdgcn_mfma_f32_16x16x32_bf16(af, bfr, acc[nf], 0, 0, 0);
      }
    }
  };

  // prologue: Wpair(0):6, X(0):4, X(1):4  -> 14 outstanding per wave
  STAGE_WP(0);
  STAGE_X(0);
  STAGE_X(1);

  for (int j = 0; j < 16; ++j) {
    const int itE = j * 2;
    // even: drain Wpair(itE)+X(itE), leave X(itE+1):4 in flight
    asm volatile("s_waitcnt vmcnt(4)" ::: "memory");
    __builtin_amdgcn_s_barrier();                  // validates Wpair cross-wave
    __builtin_amdgcn_sched_barrier(0);
    if (j < 15) STAGE_WP(j + 1);                   // pair bufs freed by barrier
    COMPUTE(itE);
    asm volatile("s_waitcnt lgkmcnt(0)" ::: "memory");  // reads done before DMA reuse
    if (itE + 2 < 32) STAGE_X(itE + 2);            // late-stage into freed buf
    // odd: drain X(itE+1); W already validated by the even barrier
    if (j < 15) { asm volatile("s_waitcnt vmcnt(10)" ::: "memory"); }
    else        { asm volatile("s_waitcnt vmcnt(0)"  ::: "memory"); }
    __builtin_amdgcn_sched_barrier(0);
    COMPUTE(itE + 1);
    asm volatile("s_waitcnt lgkmcnt(0)" ::: "memory");
    if (itE + 3 < 32) STAGE_X(itE + 3);
  }

  // s0: combine the 4 k-groups of each row (lanes differing in bits 4,5)
  s0 += __shfl_xor(s0, 16, 64);
  s0 += __shfl_xor(s0, 32, 64);

  // epilogue: C col=lane&15, row=g*4+reg; a-frag nf pairs with b-frag nf+4
  #pragma unroll
  for (int r = 0; r < 4; ++r) {
    float v = 0.f;
    #pragma unroll
    for (int nf = 0; nf < 4; ++nf) {
      float av = acc[nf][r];
      float bv = acc[nf + 4][r];
      v += av / (1.f + __expf(-bv));          // a * sigmoid(b)
    }
    v += __shfl_xor(v, 1, 64);
    v += __shfl_xor(v, 2, 64);
    v += __shfl_xor(v, 4, 64);
    v += __shfl_xor(v, 8, 64);
    const int row = g * 4 + r;
    float s0r = __shfl(s0, row, 64);          // s0 lives at lanes with r15==row
    if (r15 == 0) out[tile + wv * 16 + row] = v + s0r;
  }
}

extern "C" void kernel_launch(void* const* d_in, const int* in_sizes, int n_in,
                              void* d_out, int out_size, void* d_ws, size_t ws_size,
                              hipStream_t stream) {
  const float* x    = (const float*)d_in[0];
  const float* wqkv = (const float*)d_in[1];
  const float* wz   = (const float*)d_in[2];
  const float* wb   = (const float*)d_in[3];   // dict order: w_b before w_a
  const float* wa   = (const float*)d_in[4];
  float* out = (float*)d_out;

  float* wsum = (float*)d_ws;                                   // 8 KB fp32
  unsigned short* wbf3 = (unsigned short*)((char*)d_ws + 8192); // 512 KB 8-frag W

  k_prep<<<384, 256, 0, stream>>>(wqkv, wz, wb, wa, wsum, wbf3);
  k_main<<<out_size / 128, 512, 0, stream>>>(x, wbf3, wsum, out);
}

// Round 15
// 54.848 us; speedup vs baseline: 2.6159x; 1.0238x over previous
//
#include <hip/hip_runtime.h>
#include <stdint.h>

using bf16x8_t = __attribute__((ext_vector_type(8))) __bf16;
using f32x4_t  = __attribute__((ext_vector_type(4))) float;
using u16x8_t  = __attribute__((ext_vector_type(8))) unsigned short;

#define KD 2048

static __device__ __forceinline__ unsigned short f2bf(float f) {
  union { float f; unsigned u; } v; v.f = f;
  unsigned r = v.u + 0x7fffu + ((v.u >> 16) & 1u);   // RNE
  return (unsigned short)(r >> 16);
}

// ---- single fused prep, grid 400 (R8-R10 proven) ----
// blocks 0..127:   pack 9-frag bf16 W: dst ((s*9+nf)*64+l)*8+j <->
//                  B[col=nf*16+(l&15)][k=s*32+(l>>4)*8+j]; cols 0..63=w_a, 64..127=w_b.
// blocks 128..383: ws[h]=sum_d wqkv[d][h]+wz[d][h] -> bf16 into frag-8 (col 128).
// blocks 384..399: zero frag-8 slots for lanes (l&15)!=0 (cols 129..143).
__global__ void k_prep(const float* __restrict__ wqkv, const float* __restrict__ wz,
                       const float* __restrict__ wb, const float* __restrict__ wa,
                       unsigned short* __restrict__ wbf3) {
  __shared__ float red[4][8];
  const int b = blockIdx.x, t = threadIdx.x;
  if (b < 128) {
    const int u = b * 256 + t;                   // (s,nf,l) over nf<8
    const int l = u & 63;
    const int vv = u >> 6;
    const int nf = vv & 7;
    const int s  = vv >> 3;
    const int k  = s * 32 + ((l >> 4) << 3);
    const int c  = nf * 16 + (l & 15);
    const float* src = (c < 64) ? (wa + (size_t)c * KD + k)
                                : (wb + (size_t)(c - 64) * KD + k);
    f32x4_t v0 = *(const f32x4_t*)(src);
    f32x4_t v1 = *(const f32x4_t*)(src + 4);
    u16x8_t o;
    o[0]=f2bf(v0[0]); o[1]=f2bf(v0[1]); o[2]=f2bf(v0[2]); o[3]=f2bf(v0[3]);
    o[4]=f2bf(v1[0]); o[5]=f2bf(v1[1]); o[6]=f2bf(v1[2]); o[7]=f2bf(v1[3]);
    *(u16x8_t*)(wbf3 + (size_t)((s * 9 + nf) * 64 + l) * 8) = o;
  } else if (b < 384) {
    const int bw = b - 128;                      // cols h = bw*8 .. bw*8+7
    const int c = t & 7;
    const int rg = t >> 3;                       // 0..31
    const int h = bw * 8 + c;
    float s = 0.f;
    #pragma unroll 8
    for (int i = 0; i < 40; ++i) {
      const int r = rg + 32 * i;                 // 0..1279
      const float* p = (r < 768) ? (wqkv + (size_t)r * KD)
                                 : (wz + (size_t)(r - 768) * KD);
      s += p[h];
    }
    s += __shfl_xor(s, 8, 64);
    s += __shfl_xor(s, 16, 64);
    s += __shfl_xor(s, 32, 64);
    const int lane = t & 63, wv = t >> 6;
    if (lane < 8) red[wv][lane] = s;
    __syncthreads();
    if (t < 8) {
      const float val = red[0][t] + red[1][t] + red[2][t] + red[3][t];
      const int hh = bw * 8 + t;                 // k index 0..2047
      const int s9 = hh >> 5;                    // K-step (32-granular)
      const int g  = (hh & 31) >> 3;             // k-group
      const int j  = hh & 7;
      wbf3[(size_t)((s9 * 9 + 8) * 64 + (g << 4)) * 8 + j] = f2bf(val);
    }
  } else {
    const int idx = (b - 384) * 256 + t;         // (s,l) 0..4095
    const int s = idx >> 6, l = idx & 63;
    if (l & 15) {
      u16x8_t z; z[0]=0;z[1]=0;z[2]=0;z[3]=0;z[4]=0;z[5]=0;z[6]=0;z[7]=0;
      *(u16x8_t*)(wbf3 + (size_t)((s * 9 + 8) * 64 + l) * 8) = z;
    }
  }
}

// ---- main (R10 verbatim, best measured 54.99 us): BM=128 (8 waves x 16 rows),
// BK=64, 32 K-steps, 9 W-frags x 2 k-halves. Counted-vmcnt pipeline:
// X 3-buf of 32 KB (staged 2 ahead), W 2-buf of 18 KB (1 ahead). Steady
// per-wave queue entering iter = [W(it):2-3, X(it):4, X(it+1):4] -> vmcnt(4)
// drains W(it)+X(it), leaves X(it+1) (32 KB/CU) in flight across the barrier.
// LDS: 3x32K X + 2x18K W = 132 KB -> 1 block/CU (grid 256).
__global__ __launch_bounds__(512, 1) void k_main(
    const float* __restrict__ x, const unsigned short* __restrict__ wbf3,
    float* __restrict__ out)
{
  __shared__ __align__(16) unsigned char lds[135168];  // 98304 X | 36864 W
  const int t = threadIdx.x;
  const int lane = t & 63;
  const int wv = t >> 6;          // 0..7
  const int g = lane >> 4;        // k-group 0..3
  const int r15 = lane & 15;
  const size_t tile = (size_t)blockIdx.x * 128;

  f32x4_t acc[9];
  #pragma unroll
  for (int i = 0; i < 9; ++i) acc[i] = f32x4_t{0.f, 0.f, 0.f, 0.f};

  // W stage: 18 chunks of 1KB (2 k-half steps x 9 frags, linear in wbf3);
  // wave wv takes {wv, wv+8}; waves 0,1 also take {16,17}.
  auto STAGE_W = [&](int it) {
    unsigned char* wbp = lds + 98304 + (it & 1) * 18432;
    const unsigned short* gw = wbf3 + (size_t)it * 9216 + lane * 8;
    __builtin_amdgcn_global_load_lds(
        (const __attribute__((address_space(1))) void*)(gw + wv * 512),
        (__attribute__((address_space(3))) void*)(wbp + wv * 1024), 16, 0, 0);
    __builtin_amdgcn_global_load_lds(
        (const __attribute__((address_space(1))) void*)(gw + (wv + 8) * 512),
        (__attribute__((address_space(3))) void*)(wbp + (wv + 8) * 1024), 16, 0, 0);
    if (wv < 2)
      __builtin_amdgcn_global_load_lds(
          (const __attribute__((address_space(1))) void*)(gw + (16 + wv) * 512),
          (__attribute__((address_space(3))) void*)(wbp + (16 + wv) * 1024), 16, 0, 0);
  };
  // X stage: 32 chunks of 1KB; chunk ch = rows ch*4..ch*4+3 (256 B/row).
  // Wave wv takes chunks wv*4..wv*4+3. lane l -> row ch*4+(l>>4), LDS slot
  // l&15 holds global 16B-slot (l&15)^(row&15) (XOR swizzle, involution).
  auto STAGE_X = [&](int it, int bsel) {
    unsigned char* xbp = lds + bsel * 32768;
    #pragma unroll
    for (int i = 0; i < 4; ++i) {
      const int ch = wv * 4 + i;                   // 0..31
      const int r = ch * 4 + (lane >> 4);          // row within tile 0..127
      const int c = (lane & 15) ^ (r & 15);        // source 16B slot
      const float* src = x + (tile + r) * KD + it * 64 + c * 4;
      __builtin_amdgcn_global_load_lds(
          (const __attribute__((address_space(1))) void*)src,
          (__attribute__((address_space(3))) void*)(xbp + ch * 1024), 16, 0, 0);
    }
  };
  auto COMPUTE = [&](int it, int xbsel) {
    const unsigned char* xbp = lds + xbsel * 32768;
    const unsigned char* wbp = lds + 98304 + (it & 1) * 18432;
    const int r = wv * 16 + r15;                   // 0..127 ; r&15 == r15
    const unsigned char* xr = xbp + r * 256;
    #pragma unroll
    for (int kh = 0; kh < 2; ++kh) {
      const int c0 = kh * 8 + g * 2;
      f32x4_t lo = *(const f32x4_t*)(xr + ((c0       ^ r15) * 16));
      f32x4_t hi = *(const f32x4_t*)(xr + (((c0 + 1) ^ r15) * 16));
      bf16x8_t af;
      af[0] = (__bf16)lo[0]; af[1] = (__bf16)lo[1];
      af[2] = (__bf16)lo[2]; af[3] = (__bf16)lo[3];
      af[4] = (__bf16)hi[0]; af[5] = (__bf16)hi[1];
      af[6] = (__bf16)hi[2]; af[7] = (__bf16)hi[3];
      #pragma unroll
      for (int nf = 0; nf < 9; ++nf) {
        bf16x8_t bfr = *(const bf16x8_t*)(wbp + ((kh * 9 + nf) * 64 + lane) * 16);
        acc[nf] = __builtin_amdgcn_mfma_f32_16x16x32_bf16(af, bfr, acc[nf], 0, 0, 0);
      }
    }
  };

  // prologue: per-wave queue [W(0):2-3, X(0):4, X(1):4]
  STAGE_W(0);
  STAGE_X(0, 0);
  STAGE_X(1, 1);

  int xb = 0;                                      // buffer of tile `it` (it % 3)
  for (int it = 0; it < 31; ++it) {
    // drains W(it), X(it); leaves X(it+1) (4 loads/wave = 32 KB/CU) in flight
    asm volatile("s_waitcnt vmcnt(4)" ::: "memory");
    __builtin_amdgcn_s_barrier();
    __builtin_amdgcn_sched_barrier(0);
    STAGE_W(it + 1);                               // buf (it+1)&1, freed by barrier
    if (it < 30) {
      int b2 = xb + 2; if (b2 >= 3) b2 -= 3;
      STAGE_X(it + 2, b2);                         // buf (it+2)%3, freed by barrier
    }
    COMPUTE(it, xb);
    ++xb; if (xb == 3) xb = 0;
  }
  // peeled last step: full drain
  asm volatile("s_waitcnt vmcnt(0)" ::: "memory");
  __builtin_amdgcn_s_barrier();
  __builtin_amdgcn_sched_barrier(0);
  COMPUTE(31, xb);

  // epilogue: C col=lane&15, row=g*4+reg; a-frag nf pairs with b-frag nf+4.
  // acc[8][r] (col 128) = qkv+z fold, already at the writer lane (r15==0).
  #pragma unroll
  for (int r = 0; r < 4; ++r) {
    float v = 0.f;
    #pragma unroll
    for (int nf = 0; nf < 4; ++nf) {
      float av = acc[nf][r];
      float bv = acc[nf + 4][r];
      v += av / (1.f + __expf(-bv));          // a * sigmoid(b)
    }
    v += __shfl_xor(v, 1, 64);
    v += __shfl_xor(v, 2, 64);
    v += __shfl_xor(v, 4, 64);
    v += __shfl_xor(v, 8, 64);
    if (r15 == 0) out[tile + wv * 16 + g * 4 + r] = v + acc[8][r];
  }
}

extern "C" void kernel_launch(void* const* d_in, const int* in_sizes, int n_in,
                              void* d_out, int out_size, void* d_ws, size_t ws_size,
                              hipStream_t stream) {
  const float* x    = (const float*)d_in[0];
  const float* wqkv = (const float*)d_in[1];
  const float* wz   = (const float*)d_in[2];
  const float* wb   = (const float*)d_in[3];   // dict order: w_b before w_a
  const float* wa   = (const float*)d_in[4];
  float* out = (float*)d_out;

  unsigned short* wbf3 = (unsigned short*)d_ws;  // 64*9*64*8 shorts = 576 KB

  k_prep<<<400, 256, 0, stream>>>(wqkv, wz, wb, wa, wbf3);
  k_main<<<out_size / 128, 512, 0, stream>>>(x, wbf3, out);
}